// Round 3
// baseline (316.621 us; speedup 1.0000x reference)
//
#include <hip/hip_runtime.h>
#include <math.h>

// Problem sizes (fixed by reference): B=4, T=2048, G=8, D=128, V=1024
#define BT 8192      // B*T tokens
#define NG 8
#define ND 128
#define NV 1024

// GEMM-argmin tiling
#define BM 128       // tokens per block
#define BN 128       // codes per block
#define BK 16        // k (d) chunk in LDS
#define LDR 20       // padded row stride (floats): 20 ≡ 4 mod 32 -> banks spread

// d_out layout (float32, concatenated in return order):
//   [0, 65536)              ids (B,T,G) as float (-1 for padded)
//   [65536, 65536+8388608)  quantized_st (B,T,G*D)
//   [+0,+1,+2]              kmeans_loss, commitment_loss, total_loss
#define OUT_IDS 0
#define OUT_Q   65536
#define OUT_L   (65536 + 8388608)

// ws layout (floats): c2[8192] | x2[65536] | ids[65536] (int) | loss[8192]
#define WSF_C2   0
#define WSF_X2   8192
#define WSF_IDS  (8192 + 65536)
#define WSF_LOSS (8192 + 65536 + 65536)

// ---------------------------------------------------------------------------
// Kernel 1: c2[v*8+g] = sum_d codebook[v][g][d]^2 (numpy-pairwise 8-acc order)
// ---------------------------------------------------------------------------
__global__ __launch_bounds__(256) void c2_kernel(const float* __restrict__ cb,
                                                 float* __restrict__ c2) {
    int idx = blockIdx.x * 256 + threadIdx.x;   // idx = v*8 + g, < 8192
    const float* row = cb + (size_t)idx * ND;
    float r[8];
#pragma unroll
    for (int j = 0; j < 8; ++j) r[j] = 0.0f;
#pragma unroll
    for (int k = 0; k < 16; ++k) {
#pragma unroll
        for (int j = 0; j < 8; ++j) {
            float c = row[k * 8 + j];
            float p = __fmul_rn(c, c);
            r[j] = __fadd_rn(r[j], p);
        }
    }
    c2[idx] = __fadd_rn(
        __fadd_rn(__fadd_rn(r[0], r[1]), __fadd_rn(r[2], r[3])),
        __fadd_rn(__fadd_rn(r[4], r[5]), __fadd_rn(r[6], r[7])));
}

// ---------------------------------------------------------------------------
// Kernel 2: x2[n*8+g] = sum_d x[n][g][d]^2
// ---------------------------------------------------------------------------
__global__ __launch_bounds__(256) void x2_kernel(const float* __restrict__ x,
                                                 float* __restrict__ x2o) {
    int idx = blockIdx.x * 256 + threadIdx.x;   // n*8+g
    const float4* xr = (const float4*)(x + (size_t)idx * ND);
    float r[8];
#pragma unroll
    for (int j = 0; j < 8; ++j) r[j] = 0.0f;
#pragma unroll
    for (int i = 0; i < 32; ++i) {
        float4 v = xr[i];
        int j0 = (i * 4) & 7;
        r[j0 + 0] = __fadd_rn(r[j0 + 0], __fmul_rn(v.x, v.x));
        r[j0 + 1] = __fadd_rn(r[j0 + 1], __fmul_rn(v.y, v.y));
        r[j0 + 2] = __fadd_rn(r[j0 + 2], __fmul_rn(v.z, v.z));
        r[j0 + 3] = __fadd_rn(r[j0 + 3], __fmul_rn(v.w, v.w));
    }
    x2o[idx] = __fadd_rn(
        __fadd_rn(__fadd_rn(r[0], r[1]), __fadd_rn(r[2], r[3])),
        __fadd_rn(__fadd_rn(r[4], r[5]), __fadd_rn(r[6], r[7])));
}

// ---------------------------------------------------------------------------
// Kernel 3: register-tiled GEMM + partial argmin, all-b128 LDS traffic.
// Layout: As/Bs row-major [128][LDR=20]; fragments read ALONG k (float4 = 4
// k-steps). Interleaved micro-tile: tok = rg + 16*i, code = cg + 16*j ->
// lane bank-starts {0,20,8,28,16,4,24,12} mod 32: conflict-free b128 reads.
// Per-(tok,code) fmaf chain sequential in d: bitwise-identical to R1/R2.
// ---------------------------------------------------------------------------
__global__ __launch_bounds__(256, 3) void argmin_gemm(
    const float* __restrict__ x, const float* __restrict__ cb,
    const float* __restrict__ c2w, const float* __restrict__ x2w,
    float2* __restrict__ part) {
    __shared__ float As[BM * LDR];
    __shared__ float Bs[BN * LDR];

    const int tid = threadIdx.x;
    const int b = blockIdx.x;
    const int bn = b & 7;           // code tile
    const int g = (b >> 3) & 7;     // group
    const int tm = b >> 6;          // token tile
    const int tok0 = tm * BM;
    const int vbase = bn * BN;

    const int w = tid >> 6, lane = tid & 63;
    const int rg = ((w & 1) << 3) | (lane & 7);    // token group [0,16)
    const int cg = ((w >> 1) << 3) | (lane >> 3);  // code group  [0,16)

    float acc[8][8];
#pragma unroll
    for (int i = 0; i < 8; ++i)
#pragma unroll
        for (int j = 0; j < 8; ++j) acc[i][j] = 0.0f;

    const int r0 = tid >> 2;        // staging row [0,64)
    const int d40 = tid & 3;        // float4 slot within BK

#pragma unroll 1
    for (int kc = 0; kc < ND / BK; ++kc) {
        const float* xs = x + ((size_t)(tok0 + r0) * NG + g) * ND + kc * BK + d40 * 4;
        const float* cs = cb + ((size_t)(vbase + r0) * NG + g) * ND + kc * BK + d40 * 4;
        float4 va0 = *(const float4*)xs;
        float4 va1 = *(const float4*)(xs + (size_t)64 * NG * ND);
        float4 vc0 = *(const float4*)cs;
        float4 vc1 = *(const float4*)(cs + (size_t)64 * NG * ND);
        __syncthreads();
        *(float4*)&As[r0 * LDR + d40 * 4] = va0;
        *(float4*)&As[(r0 + 64) * LDR + d40 * 4] = va1;
        *(float4*)&Bs[r0 * LDR + d40 * 4] = vc0;
        *(float4*)&Bs[(r0 + 64) * LDR + d40 * 4] = vc1;
        __syncthreads();

#pragma unroll
        for (int kb = 0; kb < BK / 4; ++kb) {
            float4 bf[8];
#pragma unroll
            for (int j = 0; j < 8; ++j)
                bf[j] = *(const float4*)&Bs[(cg + 16 * j) * LDR + kb * 4];
#pragma unroll
            for (int i = 0; i < 8; ++i) {
                float4 af = *(const float4*)&As[(rg + 16 * i) * LDR + kb * 4];
#pragma unroll
                for (int j = 0; j < 8; ++j) {
                    float t = fmaf(af.x, bf[j].x, acc[i][j]);
                    t = fmaf(af.y, bf[j].y, t);
                    t = fmaf(af.z, bf[j].z, t);
                    acc[i][j] = fmaf(af.w, bf[j].w, t);
                }
            }
        }
    }

    // epilogue: dist = (x2 - 2*s) + c2; per-thread argmin over its 8 codes
    float c2r[8];
#pragma unroll
    for (int j = 0; j < 8; ++j)
        c2r[j] = c2w[(size_t)(vbase + cg + 16 * j) * NG + g];

    __syncthreads();   // done reading As/Bs — reuse LDS for reduction
    float* redD = As;                 // [cg][tok] 16 x (stride 132)
    int* redI = (int*)Bs;

#pragma unroll
    for (int i = 0; i < 8; ++i) {
        int tok = rg + 16 * i;
        float x2v = x2w[(size_t)(tok0 + tok) * NG + g];
        float best = INFINITY;
        int bid = 0;
#pragma unroll
        for (int j = 0; j < 8; ++j) {   // code = cg + 16*j, ascending in j
            float d = __fadd_rn(__fsub_rn(x2v, __fmul_rn(2.0f, acc[i][j])), c2r[j]);
            if (d < best) { best = d; bid = cg + 16 * j; }
        }
        redD[cg * 132 + tok] = best;
        redI[cg * 132 + tok] = bid;
    }
    __syncthreads();

    if (tid < BM) {
        int tok = tid;
        float best = INFINITY;
        int bid = 0;
#pragma unroll
        for (int c = 0; c < 16; ++c) {
            float d = redD[c * 132 + tok];
            if (d < best) { best = d; bid = redI[c * 132 + tok]; }
        }
        float2 p;
        p.x = best;
        p.y = __int_as_float(vbase + bid);
        part[((size_t)(tok0 + tok) * NG + g) * 8 + bn] = p;
    }
}

// ---------------------------------------------------------------------------
// Kernel 4: reduce partial argmins across the 8 code tiles (ascending)
// ---------------------------------------------------------------------------
__global__ __launch_bounds__(256) void reduce_kernel(
    const float2* __restrict__ part, const int* __restrict__ pad,
    int* __restrict__ ws_ids, float* __restrict__ out_ids) {
    int idx = blockIdx.x * 256 + threadIdx.x;  // n*8+g
    int n = idx >> 3;
    float best = INFINITY;
    int bid = 0;
#pragma unroll
    for (int bnn = 0; bnn < 8; ++bnn) {
        float2 p = part[(size_t)idx * 8 + bnn];
        if (p.x < best) { best = p.x; bid = __float_as_int(p.y); }
    }
    ws_ids[idx] = bid;
    out_ids[idx] = pad[n] ? -1.0f : (float)bid;
}

// ---------------------------------------------------------------------------
// Kernel 5: gather quantized (masked), write quantized_st, per-token loss
// ---------------------------------------------------------------------------
__global__ __launch_bounds__(256) void gather_kernel(
    const float* __restrict__ x, const int* __restrict__ pad,
    const float* __restrict__ cb, const int* __restrict__ ws_ids,
    float* __restrict__ out_q, float* __restrict__ ws_loss) {
    const int n = blockIdx.x;
    const int tid = threadIdx.x;
    const int g = tid >> 5;
    const int d4 = tid & 31;
    const int p = pad[n];

    float4 q = make_float4(0.f, 0.f, 0.f, 0.f);
    float s = 0.f;
    if (!p) {
        int id = ws_ids[n * NG + g];
        q = ((const float4*)(cb + ((size_t)id * NG + g) * ND))[d4];
        float4 a = ((const float4*)(x + (size_t)n * (NG * ND)))[tid];
        float e0 = q.x - a.x, e1 = q.y - a.y, e2 = q.z - a.z, e3 = q.w - a.w;
        s = e0 * e0 + e1 * e1 + e2 * e2 + e3 * e3;
    }
    ((float4*)(out_q + (size_t)n * (NG * ND)))[tid] = q;

    for (int off = 32; off > 0; off >>= 1) s += __shfl_down(s, off);
    __shared__ float red[4];
    int w = tid >> 6, lane = tid & 63;
    if (lane == 0) red[w] = s;
    __syncthreads();
    if (tid == 0) ws_loss[n] = (red[0] + red[1]) + (red[2] + red[3]);
}

// ---------------------------------------------------------------------------
// Kernel 6: finalize losses (deterministic)
// ---------------------------------------------------------------------------
__global__ __launch_bounds__(256) void final_kernel(
    const int* __restrict__ pad, const float* __restrict__ ws_loss,
    float* __restrict__ out_l) {
    __shared__ float sr[256];
    __shared__ int mr[256];
    const int tid = threadIdx.x;
    float s = 0.f;
    int m = 0;
    for (int i = tid; i < BT; i += 256) {
        s += ws_loss[i];
        m += 1 - pad[i];
    }
    sr[tid] = s;
    mr[tid] = m;
    __syncthreads();
    for (int st = 128; st > 0; st >>= 1) {
        if (tid < st) { sr[tid] += sr[tid + st]; mr[tid] += mr[tid + st]; }
        __syncthreads();
    }
    if (tid == 0) {
        float k = sr[0] / (float)mr[0];
        out_l[0] = k;
        out_l[1] = k;
        out_l[2] = k + k;
    }
}

// ---------------------------------------------------------------------------
extern "C" void kernel_launch(void* const* d_in, const int* in_sizes, int n_in,
                              void* d_out, int out_size, void* d_ws, size_t ws_size,
                              hipStream_t stream) {
    const float* x = (const float*)d_in[0];    // (4,2048,1024) f32
    const int* pad = (const int*)d_in[1];      // (4,2048) i32
    const float* cb = (const float*)d_in[2];   // (1024,8,128) f32
    float* out = (float*)d_out;
    float* ws = (float*)d_ws;

    float* ws_c2 = ws + WSF_C2;
    float* ws_x2 = ws + WSF_X2;
    int* ws_ids = (int*)(ws + WSF_IDS);
    float* ws_loss = ws + WSF_LOSS;

    // partial argmins parked in the quantized-output region (overwritten by
    // gather_kernel afterwards): 65536 * 8 * sizeof(float2) = 4 MB << 33 MB
    float2* part = (float2*)(out + OUT_Q);

    c2_kernel<<<NV * NG / 256, 256, 0, stream>>>(cb, ws_c2);
    x2_kernel<<<BT * NG / 256, 256, 0, stream>>>(x, ws_x2);
    argmin_gemm<<<(BT / BM) * (NV / BN) * NG, 256, 0, stream>>>(x, cb, ws_c2,
                                                                ws_x2, part);
    reduce_kernel<<<BT * NG / 256, 256, 0, stream>>>(part, pad, ws_ids,
                                                     out + OUT_IDS);
    gather_kernel<<<BT, 256, 0, stream>>>(x, pad, cb, ws_ids, out + OUT_Q, ws_loss);
    final_kernel<<<1, 256, 0, stream>>>(pad, ws_loss, out + OUT_L);
}

// Round 4
// 260.391 us; speedup vs baseline: 1.2159x; 1.2159x over previous
//
#include <hip/hip_runtime.h>
#include <math.h>

typedef short short8 __attribute__((ext_vector_type(8)));
typedef float f32x4 __attribute__((ext_vector_type(4)));
typedef unsigned short u16;
typedef unsigned int u32;

// Problem sizes: B=4, T=2048, G=8, D=128, V=1024
#define BT 8192
#define NG 8
#define ND 128
#define NV 1024
#define MARGIN 0.05f

// d_out layout (float32): ids[65536] | quantized_st[8388608] | 3 losses
#define OUT_IDS 0
#define OUT_Q   65536
#define OUT_L   (65536 + 8388608)
// xh/xl (bf16) parked in d_out: xh = floats [0, 4.19M), xl = [4.19M, 8.39M).
// Consumed by mfma_gemm BEFORE reduce/gather overwrite ids/Q regions.

// ws float offsets (~13.5 MB total)
#define OFF_C2    0
#define OFF_X2    8192
#define OFF_IDS   73728
#define OFF_LOSS  139264
#define OFF_CNT   147456
#define OFF_FLAGS 147460
#define OFF_CBH   213000
#define OFF_CBL   737288
#define OFF_PART  1261576   // 65536*8 float4

// ---------------------------------------------------------------------------
// c2[v*8+g] = sum_d cb^2 (numpy-pairwise 8-acc order, mul+add)
// ---------------------------------------------------------------------------
__global__ __launch_bounds__(256) void c2_kernel(const float* __restrict__ cb,
                                                 float* __restrict__ c2) {
    int idx = blockIdx.x * 256 + threadIdx.x;
    const float* row = cb + (size_t)idx * ND;
    float r[8];
#pragma unroll
    for (int j = 0; j < 8; ++j) r[j] = 0.0f;
#pragma unroll
    for (int k = 0; k < 16; ++k)
#pragma unroll
        for (int j = 0; j < 8; ++j) {
            float c = row[k * 8 + j];
            r[j] = __fadd_rn(r[j], __fmul_rn(c, c));
        }
    c2[idx] = __fadd_rn(
        __fadd_rn(__fadd_rn(r[0], r[1]), __fadd_rn(r[2], r[3])),
        __fadd_rn(__fadd_rn(r[4], r[5]), __fadd_rn(r[6], r[7])));
}

// ---------------------------------------------------------------------------
// x2[n*8+g] = sum_d x^2
// ---------------------------------------------------------------------------
__global__ __launch_bounds__(256) void x2_kernel(const float* __restrict__ x,
                                                 float* __restrict__ x2o) {
    int idx = blockIdx.x * 256 + threadIdx.x;
    const float4* xr = (const float4*)(x + (size_t)idx * ND);
    float r[8];
#pragma unroll
    for (int j = 0; j < 8; ++j) r[j] = 0.0f;
#pragma unroll
    for (int i = 0; i < 32; ++i) {
        float4 v = xr[i];
        int j0 = (i * 4) & 7;
        r[j0 + 0] = __fadd_rn(r[j0 + 0], __fmul_rn(v.x, v.x));
        r[j0 + 1] = __fadd_rn(r[j0 + 1], __fmul_rn(v.y, v.y));
        r[j0 + 2] = __fadd_rn(r[j0 + 2], __fmul_rn(v.z, v.z));
        r[j0 + 3] = __fadd_rn(r[j0 + 3], __fmul_rn(v.w, v.w));
    }
    x2o[idx] = __fadd_rn(
        __fadd_rn(__fadd_rn(r[0], r[1]), __fadd_rn(r[2], r[3])),
        __fadd_rn(__fadd_rn(r[4], r[5]), __fadd_rn(r[6], r[7])));
}

// ---------------------------------------------------------------------------
// bf16 split: h = bf16_rne(v), l = bf16_rne(v - h).  8 elems/thread.
// ---------------------------------------------------------------------------
__global__ __launch_bounds__(256) void convert_split(const float* __restrict__ src,
                                                     u16* __restrict__ dh,
                                                     u16* __restrict__ dl) {
    int idx = blockIdx.x * 256 + threadIdx.x;
    const float4* sr = (const float4*)(src) + (size_t)idx * 2;
    float4 a = sr[0], b = sr[1];
    float v[8] = {a.x, a.y, a.z, a.w, b.x, b.y, b.z, b.w};
    short8 h, l;
#pragma unroll
    for (int j = 0; j < 8; ++j) {
        u32 u = __float_as_uint(v[j]);
        u32 hb = (u + 0x7FFFu + ((u >> 16) & 1u)) >> 16;
        float hf = __uint_as_float(hb << 16);
        float r = v[j] - hf;
        u32 ur = __float_as_uint(r);
        u32 lb = (ur + 0x7FFFu + ((ur >> 16) & 1u)) >> 16;
        h[j] = (short)hb;
        l[j] = (short)lb;
    }
    *(short8*)(dh + (size_t)idx * 8) = h;
    *(short8*)(dl + (size_t)idx * 8) = l;
}

// ---------------------------------------------------------------------------
// MFMA distance GEMM + top-2 argmin partials.
// Block: 128 tok x 128 codes, 4 waves (2x2 quadrants of 64x64).
// s = xh*ch + xh*cl + xl*ch  (3 chained mfma_f32_16x16x32_bf16 per acc tile).
// B (codebook) tiles staged in LDS with XOR swizzle ((row&7)<<4 bytes);
// A-hi frags hoisted to VGPRs for all kk; A-lo loaded per kk (L2-hot).
// Frag layout: A row=lane&15, k=kk*32+(lane>>4)*8+j ; B col-row symmetric;
// D col=lane&15, row=(lane>>4)*4+reg  [m89-verified].
// ---------------------------------------------------------------------------
__global__ __launch_bounds__(256, 2) void mfma_gemm(
    const u16* __restrict__ xh, const u16* __restrict__ xl,
    const u16* __restrict__ cbh, const u16* __restrict__ cbl,
    const float* __restrict__ c2w, const float* __restrict__ x2w,
    float4* __restrict__ part) {
    __shared__ short Bh[128 * 128];
    __shared__ short Bl[128 * 128];
    __shared__ float4 red[256];

    const int tid = threadIdx.x;
    const int b = blockIdx.x;
    const int cn = b & 7;
    const int g = (b >> 3) & 7;
    const int tm = b >> 6;
    const int tok0 = tm * 128;
    const int vb0 = cn * 128;
    const int lane = tid & 63;
    const int w = tid >> 6;
    const int wr = w & 1, wc = w >> 1;
    const int l15 = lane & 15, l4 = lane >> 4;

    // stage B tiles (swizzled)
#pragma unroll
    for (int i = 0; i < 8; ++i) {
        int s = i * 256 + tid;
        int row = s >> 4, k16 = s & 15;
        size_t gb = ((size_t)(vb0 + row) * NG + g) * ND + k16 * 8;
        int lo = row * 128 + ((k16 ^ (row & 7)) << 3);
        *(short8*)&Bh[lo] = *(const short8*)(cbh + gb);
        *(short8*)&Bl[lo] = *(const short8*)(cbl + gb);
    }

    // hoist A-hi frags
    short8 ah[4][4];   // [kk][ti]
#pragma unroll
    for (int kk = 0; kk < 4; ++kk)
#pragma unroll
        for (int ti = 0; ti < 4; ++ti) {
            size_t ar = ((size_t)(tok0 + wr * 64 + ti * 16 + l15) * NG + g) * ND
                        + kk * 32 + l4 * 8;
            ah[kk][ti] = *(const short8*)(xh + ar);
        }

    f32x4 acc[4][4];
#pragma unroll
    for (int i = 0; i < 4; ++i)
#pragma unroll
        for (int j = 0; j < 4; ++j) acc[i][j] = (f32x4){0.f, 0.f, 0.f, 0.f};

    __syncthreads();

#pragma unroll
    for (int kk = 0; kk < 4; ++kk) {
        short8 al[4], bh[4], bl[4];
#pragma unroll
        for (int ti = 0; ti < 4; ++ti) {
            size_t ar = ((size_t)(tok0 + wr * 64 + ti * 16 + l15) * NG + g) * ND
                        + kk * 32 + l4 * 8;
            al[ti] = *(const short8*)(xl + ar);
        }
#pragma unroll
        for (int tj = 0; tj < 4; ++tj) {
            int br = wc * 64 + tj * 16 + l15;
            int off = br * 128 + (((kk * 4 + l4) ^ (br & 7)) << 3);
            bh[tj] = *(short8*)&Bh[off];
            bl[tj] = *(short8*)&Bl[off];
        }
#pragma unroll
        for (int ti = 0; ti < 4; ++ti)
#pragma unroll
            for (int tj = 0; tj < 4; ++tj)
                acc[ti][tj] = __builtin_amdgcn_mfma_f32_16x16x32_bf16(
                    ah[kk][ti], bh[tj], acc[ti][tj], 0, 0, 0);
#pragma unroll
        for (int ti = 0; ti < 4; ++ti)
#pragma unroll
            for (int tj = 0; tj < 4; ++tj)
                acc[ti][tj] = __builtin_amdgcn_mfma_f32_16x16x32_bf16(
                    ah[kk][ti], bl[tj], acc[ti][tj], 0, 0, 0);
#pragma unroll
        for (int ti = 0; ti < 4; ++ti)
#pragma unroll
            for (int tj = 0; tj < 4; ++tj)
                acc[ti][tj] = __builtin_amdgcn_mfma_f32_16x16x32_bf16(
                    al[ti], bh[tj], acc[ti][tj], 0, 0, 0);
    }

    // epilogue: dist = (x2 - 2s) + c2, per-token top-2 over this block's codes
    float c2r[4];
#pragma unroll
    for (int tj = 0; tj < 4; ++tj)
        c2r[tj] = c2w[(size_t)(vb0 + wc * 64 + tj * 16 + l15) * NG + g];

#pragma unroll
    for (int ti = 0; ti < 4; ++ti) {
#pragma unroll
        for (int r = 0; r < 4; ++r) {
            int tokl = wr * 64 + ti * 16 + l4 * 4 + r;
            float x2v = x2w[(size_t)(tok0 + tokl) * NG + g];
            float d1 = INFINITY, d2 = INFINITY;
            int id = 0;
#pragma unroll
            for (int tj = 0; tj < 4; ++tj) {
                float sv = acc[ti][tj][r];
                float d = __fadd_rn(__fsub_rn(x2v, __fmul_rn(2.0f, sv)), c2r[tj]);
                if (d < d1) { d2 = d1; d1 = d; id = vb0 + wc * 64 + tj * 16 + l15; }
                else d2 = fminf(d2, d);
            }
#pragma unroll
            for (int m = 1; m < 16; m <<= 1) {
                float od1 = __shfl_xor(d1, m);
                int oid = __shfl_xor(id, m);
                float od2 = __shfl_xor(d2, m);
                if (od1 < d1) { d2 = fminf(d1, od2); d1 = od1; id = oid; }
                else d2 = fminf(d2, od1);
            }
            if (l15 == 0) red[wc * 128 + tokl] =
                make_float4(d1, __int_as_float(id), d2, 0.f);
        }
    }
    __syncthreads();
    if (tid < 128) {
        float4 a = red[tid], c = red[128 + tid];
        float d1 = a.x, d2 = a.z;
        int id = __float_as_int(a.y);
        if (c.x < d1) { d2 = fminf(d1, c.z); d1 = c.x; id = __float_as_int(c.y); }
        else d2 = fminf(d2, c.x);
        part[((size_t)(tok0 + tid) * NG + g) * 8 + cn] =
            make_float4(d1, __int_as_float(id), d2, 0.f);
    }
}

// ---------------------------------------------------------------------------
// merge 8 code-tile partials; flag near-ties (gap < MARGIN) for exact recheck
// ---------------------------------------------------------------------------
__global__ __launch_bounds__(256) void reduce_flag(
    const float4* __restrict__ part, const int* __restrict__ pad,
    int* __restrict__ ws_ids, float* __restrict__ out_ids,
    int* __restrict__ cnt, int* __restrict__ flags) {
    int idx = blockIdx.x * 256 + threadIdx.x;
    const float4* p = part + (size_t)idx * 8;
    float4 a = p[0];
    float d1 = a.x, d2 = a.z;
    int id = __float_as_int(a.y);
#pragma unroll
    for (int s = 1; s < 8; ++s) {
        float4 c = p[s];
        if (c.x < d1) { d2 = fminf(d1, c.z); d1 = c.x; id = __float_as_int(c.y); }
        else d2 = fminf(d2, c.x);
    }
    ws_ids[idx] = id;
    out_ids[idx] = pad[idx >> 3] ? -1.0f : (float)id;
    if (d2 - d1 < MARGIN) {
        int pos = atomicAdd(cnt, 1);
        flags[pos] = idx;
    }
}

// ---------------------------------------------------------------------------
// exact fp32 recheck for flagged (token,g): R1-identical arithmetic.
// One wave per flagged pair; lane handles 16 codes (lane + 64*j, ascending).
// ---------------------------------------------------------------------------
__global__ __launch_bounds__(256, 1) void recheck(
    const float* __restrict__ x, const int* __restrict__ pad,
    const float* __restrict__ cb, const float* __restrict__ c2w,
    const float* __restrict__ x2w, const int* __restrict__ cnt,
    const int* __restrict__ flags, int* __restrict__ ws_ids,
    float* __restrict__ out_ids) {
    const int lane = threadIdx.x & 63;
    const int wid = (blockIdx.x * 256 + threadIdx.x) >> 6;
    const int nw = gridDim.x * 4;
    const int n_f = cnt[0];
    for (int f = wid; f < n_f; f += nw) {
        int idx = flags[f];
        int g = idx & 7;
        const float4* xr = (const float4*)(x + (size_t)idx * ND);
        float4 xv[32];
#pragma unroll
        for (int i = 0; i < 32; ++i) xv[i] = xr[i];
        float x2v = x2w[idx];
        float best = INFINITY;
        int bid = 0;
        for (int j = 0; j < 16; ++j) {
            int c = lane + 64 * j;
            const float4* cr = (const float4*)(cb + ((size_t)c * NG + g) * ND);
            float s = 0.f;
#pragma unroll
            for (int i = 0; i < 32; ++i) {
                float4 q = cr[i];
                s = fmaf(xv[i].x, q.x, s);
                s = fmaf(xv[i].y, q.y, s);
                s = fmaf(xv[i].z, q.z, s);
                s = fmaf(xv[i].w, q.w, s);
            }
            float d = __fadd_rn(__fsub_rn(x2v, __fmul_rn(2.0f, s)),
                                c2w[(size_t)c * NG + g]);
            if (d < best) { best = d; bid = c; }
        }
#pragma unroll
        for (int m = 1; m < 64; m <<= 1) {
            float od = __shfl_xor(best, m);
            int ob = __shfl_xor(bid, m);
            if (od < best || (od == best && ob < bid)) { best = od; bid = ob; }
        }
        if (lane == 0) {
            ws_ids[idx] = bid;
            out_ids[idx] = pad[idx >> 3] ? -1.0f : (float)bid;
        }
    }
}

// ---------------------------------------------------------------------------
// gather quantized (masked), write quantized_st, per-token loss partial
// ---------------------------------------------------------------------------
__global__ __launch_bounds__(256) void gather_kernel(
    const float* __restrict__ x, const int* __restrict__ pad,
    const float* __restrict__ cb, const int* __restrict__ ws_ids,
    float* __restrict__ out_q, float* __restrict__ ws_loss) {
    const int n = blockIdx.x;
    const int tid = threadIdx.x;
    const int g = tid >> 5;
    const int d4 = tid & 31;
    const int p = pad[n];

    float4 q = make_float4(0.f, 0.f, 0.f, 0.f);
    float s = 0.f;
    if (!p) {
        int id = ws_ids[n * NG + g];
        q = ((const float4*)(cb + ((size_t)id * NG + g) * ND))[d4];
        float4 a = ((const float4*)(x + (size_t)n * (NG * ND)))[tid];
        float e0 = q.x - a.x, e1 = q.y - a.y, e2 = q.z - a.z, e3 = q.w - a.w;
        s = e0 * e0 + e1 * e1 + e2 * e2 + e3 * e3;
    }
    ((float4*)(out_q + (size_t)n * (NG * ND)))[tid] = q;

    for (int off = 32; off > 0; off >>= 1) s += __shfl_down(s, off);
    __shared__ float red[4];
    int w = tid >> 6, lane = tid & 63;
    if (lane == 0) red[w] = s;
    __syncthreads();
    if (tid == 0) ws_loss[n] = (red[0] + red[1]) + (red[2] + red[3]);
}

// ---------------------------------------------------------------------------
__global__ __launch_bounds__(256) void final_kernel(
    const int* __restrict__ pad, const float* __restrict__ ws_loss,
    float* __restrict__ out_l) {
    __shared__ float sr[256];
    __shared__ int mr[256];
    const int tid = threadIdx.x;
    float s = 0.f;
    int m = 0;
    for (int i = tid; i < BT; i += 256) {
        s += ws_loss[i];
        m += 1 - pad[i];
    }
    sr[tid] = s;
    mr[tid] = m;
    __syncthreads();
    for (int st = 128; st > 0; st >>= 1) {
        if (tid < st) { sr[tid] += sr[tid + st]; mr[tid] += mr[tid + st]; }
        __syncthreads();
    }
    if (tid == 0) {
        float k = sr[0] / (float)mr[0];
        out_l[0] = k;
        out_l[1] = k;
        out_l[2] = k + k;
    }
}

// ---------------------------------------------------------------------------
extern "C" void kernel_launch(void* const* d_in, const int* in_sizes, int n_in,
                              void* d_out, int out_size, void* d_ws, size_t ws_size,
                              hipStream_t stream) {
    const float* x = (const float*)d_in[0];    // (4,2048,1024) f32
    const int* pad = (const int*)d_in[1];      // (4,2048) i32
    const float* cb = (const float*)d_in[2];   // (1024,8,128) f32
    float* out = (float*)d_out;
    float* ws = (float*)d_ws;

    float* ws_c2 = ws + OFF_C2;
    float* ws_x2 = ws + OFF_X2;
    int* ws_ids = (int*)(ws + OFF_IDS);
    float* ws_loss = ws + OFF_LOSS;
    int* ws_cnt = (int*)(ws + OFF_CNT);
    int* ws_flags = (int*)(ws + OFF_FLAGS);
    u16* cbh = (u16*)(ws + OFF_CBH);
    u16* cbl = (u16*)(ws + OFF_CBL);
    float4* part = (float4*)(ws + OFF_PART);
    u16* xh = (u16*)out;                        // parked in d_out (consumed early)
    u16* xl = xh + (size_t)BT * NG * ND;

    hipMemsetAsync(ws_cnt, 0, 4, stream);
    c2_kernel<<<NV * NG / 256, 256, 0, stream>>>(cb, ws_c2);
    x2_kernel<<<BT * NG / 256, 256, 0, stream>>>(x, ws_x2);
    convert_split<<<BT * NG * ND / 8 / 256, 256, 0, stream>>>(x, xh, xl);
    convert_split<<<NV * NG * ND / 8 / 256, 256, 0, stream>>>(cb, cbh, cbl);
    mfma_gemm<<<(BT / 128) * (NV / 128) * NG, 256, 0, stream>>>(
        xh, xl, cbh, cbl, ws_c2, ws_x2, part);
    reduce_flag<<<BT * NG / 256, 256, 0, stream>>>(part, pad, ws_ids,
                                                   out + OUT_IDS, ws_cnt, ws_flags);
    recheck<<<128, 256, 0, stream>>>(x, pad, cb, ws_c2, ws_x2, ws_cnt, ws_flags,
                                     ws_ids, out + OUT_IDS);
    gather_kernel<<<BT, 256, 0, stream>>>(x, pad, cb, ws_ids, out + OUT_Q, ws_loss);
    final_kernel<<<1, 256, 0, stream>>>(pad, ws_loss, out + OUT_L);
}